// Round 1
// baseline (211.735 us; speedup 1.0000x reference)
//
#include <hip/hip_runtime.h>
#include <math.h>

#define N_NODES 4096
#define DIM     128
#define NPAIRS  32768
#define NEVENTS 4096
#define NTYPES  3
#define NREL    4
#define NNEIGH  16
#define WORDS   64   // 4096 bits / 64

// ---------------- K0: sum_alpha = sum(exp(-theta*(1 - t_events))) ----------------
__global__ __launch_bounds__(256) void k_sum_alpha(const float* __restrict__ t_events,
                                                   const float* __restrict__ theta_p,
                                                   float* __restrict__ out) {
    __shared__ float red[256];
    float th = theta_p[0];
    float acc = 0.f;
    for (int i = threadIdx.x; i < NEVENTS; i += 256)
        acc += expf(-th * (1.0f - t_events[i]));
    red[threadIdx.x] = acc;
    __syncthreads();
    for (int s = 128; s > 0; s >>= 1) {
        if (threadIdx.x < s) red[threadIdx.x] += red[threadIdx.x + s];
        __syncthreads();
    }
    if (threadIdx.x == 0) out[0] = red[0];
}

// ---------------- K1: adjacency row -> 64 x u64 bitmask + degree ----------------
__global__ __launch_bounds__(256) void k_mask(const int* __restrict__ adj,
                                              unsigned long long* __restrict__ mask,
                                              float* __restrict__ degf) {
    int row  = blockIdx.x;
    int lane = threadIdx.x & 63;
    int wave = threadIdx.x >> 6;
    const int* arow = adj + (size_t)row * N_NODES;
    unsigned int cnt = 0;
    for (int w = wave; w < WORDS; w += 4) {
        int v = arow[w * 64 + lane];
        unsigned long long b = __ballot(v != 0);
        if (lane == 0) {
            mask[(size_t)row * WORDS + w] = b;
            cnt += __popcll(b);
        }
    }
    __shared__ unsigned int wred[4];
    if (lane == 0) wred[wave] = cnt;
    __syncthreads();
    if (threadIdx.x == 0)
        degf[row] = (float)(wred[0] + wred[1] + wred[2] + wred[3]);
}

// ---------------- K2: tri via bitset intersect, C = 2*tri/(deg*(deg-1)) ----------------
__global__ __launch_bounds__(256) void k_clust(const unsigned long long* __restrict__ mask,
                                               const float* __restrict__ degf,
                                               float* __restrict__ C) {
    int wave = threadIdx.x >> 6;
    int lane = threadIdx.x & 63;
    int node = blockIdx.x * 4 + wave;
    const unsigned long long* mrow = mask + (size_t)node * WORDS;
    unsigned long long my = mrow[lane];
    unsigned int acc = 0;
    for (int w = 0; w < WORDS; ++w) {
        unsigned long long word = mrow[w];  // wave-uniform
        while (word) {
            int b = __ffsll(word) - 1;
            int j = w * 64 + b;
            acc += __popcll(my & mask[(size_t)j * WORDS + lane]);
            word &= word - 1;
        }
    }
    for (int off = 32; off > 0; off >>= 1) acc += __shfl_xor(acc, off);
    if (lane == 0) {
        float dg = degf[node];
        float denom = dg * (dg - 1.0f);
        if (denom == 0.0f) denom = 1e-6f;
        C[node] = 2.0f * (float)acc / denom;
    }
}

// ---------------- K3: proj[n] = x[n] @ W_proj[type[n]]  (8 nodes/block) ----------------
__global__ __launch_bounds__(128) void k_proj(const float* __restrict__ x,
                                              const int* __restrict__ ntype,
                                              const float* __restrict__ Wp,
                                              float* __restrict__ proj) {
    int base = blockIdx.x * 8;
    int e = threadIdx.x;
    __shared__ float xs[8][DIM];
    __shared__ int ts[8];
    for (int m = 0; m < 8; ++m) xs[m][e] = x[(size_t)(base + m) * DIM + e];
    if (e < 8) ts[e] = ntype[base + e];
    __syncthreads();
    float acc[8] = {0.f, 0.f, 0.f, 0.f, 0.f, 0.f, 0.f, 0.f};
    int tloc[8];
    for (int m = 0; m < 8; ++m) tloc[m] = ts[m];
    for (int t = 0; t < NTYPES; ++t) {
        const float* W = Wp + (size_t)t * DIM * DIM;
        bool any = false;
        for (int m = 0; m < 8; ++m) any |= (tloc[m] == t);
        if (!any) continue;
        for (int d = 0; d < DIM; ++d) {
            float w = W[d * DIM + e];
            #pragma unroll
            for (int m = 0; m < 8; ++m)
                acc[m] += (tloc[m] == t ? xs[m][d] : 0.f) * w;
        }
    }
    for (int m = 0; m < 8; ++m) proj[(size_t)(base + m) * DIM + e] = acc[m];
}

// ---------------- K4: eps = sigmoid(mean_r(h_r @ W_beta[r] + b_beta[r]))  (8 nodes/block) ----------------
__global__ __launch_bounds__(128) void k_eps(const float* __restrict__ x,
                                             const int* __restrict__ nidx,
                                             const float* __restrict__ Wb,
                                             const float* __restrict__ bb,
                                             float* __restrict__ eps) {
    int base = blockIdx.x * 8;
    int d = threadIdx.x;
    __shared__ float h[8][NREL][DIM];  // 16 KB
    for (int m = 0; m < 8; ++m) {
        int n = base + m;
        for (int r = 0; r < NREL; ++r) {
            const int* idx = nidx + ((size_t)n * NREL + r) * NNEIGH;
            float s = 0.f;
            #pragma unroll
            for (int k = 0; k < NNEIGH; ++k)
                s += x[(size_t)idx[k] * DIM + d];
            h[m][r][d] = s * (1.0f / 16.0f);
        }
    }
    __syncthreads();
    int e = d;
    float acc[8] = {0.f, 0.f, 0.f, 0.f, 0.f, 0.f, 0.f, 0.f};
    for (int r = 0; r < NREL; ++r) {
        const float* W = Wb + (size_t)r * DIM * DIM;
        for (int dd = 0; dd < DIM; ++dd) {
            float w = W[dd * DIM + e];
            #pragma unroll
            for (int m = 0; m < 8; ++m) acc[m] += h[m][r][dd] * w;
        }
    }
    float bsum = bb[e] + bb[DIM + e] + bb[2 * DIM + e] + bb[3 * DIM + e];
    for (int m = 0; m < 8; ++m) {
        float v = (acc[m] + bsum) * 0.25f;
        eps[(size_t)(base + m) * DIM + e] = 1.0f / (1.0f + expf(-v));
    }
}

// ---------------- K5: per-pair fused epilogue (one wave per pair) ----------------
__global__ __launch_bounds__(256) void k_pairs(const int* __restrict__ pairs,
                                               const unsigned long long* __restrict__ mask,
                                               const float* __restrict__ C,
                                               const float* __restrict__ proj,
                                               const float* __restrict__ eps,
                                               const float* __restrict__ x,
                                               const float* __restrict__ salpha_p,
                                               const float* __restrict__ q1p,
                                               const float* __restrict__ q2p,
                                               float* __restrict__ out) {
    int wave = threadIdx.x >> 6;
    int lane = threadIdx.x & 63;
    int p = blockIdx.x * 4 + wave;
    int pm = pairs[p * 2];
    int pn = pairs[p * 2 + 1];

    // common-neighbor weighted sum over C
    unsigned long long cw = mask[(size_t)pm * WORDS + lane] & mask[(size_t)pn * WORDS + lane];
    float csum = 0.f;
    while (cw) {
        int b = __ffsll(cw) - 1;
        csum += C[lane * 64 + b];
        cw &= cw - 1;
    }

    float s1 = 0.f, s2 = 0.f, s3 = 0.f;
    #pragma unroll
    for (int i = 0; i < 2; ++i) {
        int d = lane + i * 64;
        float dp = proj[(size_t)pm * DIM + d] - proj[(size_t)pn * DIM + d];
        s1 += dp * dp;
        float dx = x[(size_t)pm * DIM + d] - x[(size_t)pn * DIM + d];
        s2 += dx * dx;
        s3 += eps[(size_t)pm * DIM + d] * eps[(size_t)pn * DIM + d];
    }
    for (int off = 32; off > 0; off >>= 1) {
        s1 += __shfl_xor(s1, off);
        s2 += __shfl_xor(s2, off);
        s3 += __shfl_xor(s3, off);
        csum += __shfl_xor(csum, off);
    }
    if (lane == 0) {
        float lhist  = -sqrtf(s1) + salpha_p[0];
        float ltri   = csum * (-s2);
        float lneigh = s3 * (1.0f / 128.0f);
        float lam = expf(lhist + ltri + lneigh);
        float z = q1p[0] * lam + q2p[0];
        out[p] = 1.0f / (1.0f + expf(-z));
    }
}

extern "C" void kernel_launch(void* const* d_in, const int* in_sizes, int n_in,
                              void* d_out, int out_size, void* d_ws, size_t ws_size,
                              hipStream_t stream) {
    const int*   pairs    = (const int*)d_in[0];
    const int*   adj      = (const int*)d_in[1];
    const int*   nidx     = (const int*)d_in[2];
    const int*   ntype    = (const int*)d_in[3];
    const float* t_events = (const float*)d_in[4];
    const float* x        = (const float*)d_in[5];
    const float* Wp       = (const float*)d_in[6];
    const float* Wb       = (const float*)d_in[7];
    const float* bb       = (const float*)d_in[8];
    const float* theta    = (const float*)d_in[9];
    const float* q1       = (const float*)d_in[10];
    const float* q2       = (const float*)d_in[11];
    float* out = (float*)d_out;

    char* ws = (char*)d_ws;
    unsigned long long* mask = (unsigned long long*)(ws + 0);      // 2 MB
    float* deg    = (float*)(ws + 2097152);                        // 16 KB
    float* C      = (float*)(ws + 2113536);                        // 16 KB
    float* proj   = (float*)(ws + 2129920);                        // 2 MB
    float* eps    = (float*)(ws + 4227072);                        // 2 MB
    float* salpha = (float*)(ws + 6324224);                        // 4 B

    hipLaunchKernelGGL(k_sum_alpha, dim3(1),           dim3(256), 0, stream, t_events, theta, salpha);
    hipLaunchKernelGGL(k_mask,      dim3(N_NODES),     dim3(256), 0, stream, adj, mask, deg);
    hipLaunchKernelGGL(k_clust,     dim3(N_NODES / 4), dim3(256), 0, stream, mask, deg, C);
    hipLaunchKernelGGL(k_proj,      dim3(N_NODES / 8), dim3(128), 0, stream, x, ntype, Wp, proj);
    hipLaunchKernelGGL(k_eps,       dim3(N_NODES / 8), dim3(128), 0, stream, x, nidx, Wb, bb, eps);
    hipLaunchKernelGGL(k_pairs,     dim3(NPAIRS / 4),  dim3(256), 0, stream,
                       pairs, mask, C, proj, eps, x, salpha, q1, q2, out);
}

// Round 2
// 191.470 us; speedup vs baseline: 1.1058x; 1.1058x over previous
//
#include <hip/hip_runtime.h>
#include <math.h>

#define N_NODES 4096
#define DIM     128
#define NPAIRS  32768
#define NEVENTS 4096
#define NTYPES  3
#define NREL    4
#define NNEIGH  16
#define WORDS   64   // 4096 bits / 64

// ---------------- K0: sum_alpha = sum(exp(-theta*(1 - t_events))) ----------------
__global__ __launch_bounds__(256) void k_sum_alpha(const float* __restrict__ t_events,
                                                   const float* __restrict__ theta_p,
                                                   float* __restrict__ out) {
    __shared__ float red[256];
    float th = theta_p[0];
    float acc = 0.f;
    for (int i = threadIdx.x; i < NEVENTS; i += 256)
        acc += expf(-th * (1.0f - t_events[i]));
    red[threadIdx.x] = acc;
    __syncthreads();
    for (int s = 128; s > 0; s >>= 1) {
        if (threadIdx.x < s) red[threadIdx.x] += red[threadIdx.x + s];
        __syncthreads();
    }
    if (threadIdx.x == 0) out[0] = red[0];
}

// ---------------- K1: adjacency row -> 64 x u64 bitmask + degree ----------------
__global__ __launch_bounds__(256) void k_mask(const int* __restrict__ adj,
                                              unsigned long long* __restrict__ mask,
                                              float* __restrict__ degf) {
    int row  = blockIdx.x;
    int lane = threadIdx.x & 63;
    int wave = threadIdx.x >> 6;
    const int* arow = adj + (size_t)row * N_NODES;
    unsigned int cnt = 0;
    for (int w = wave; w < WORDS; w += 4) {
        int v = arow[w * 64 + lane];
        unsigned long long b = __ballot(v != 0);
        if (lane == 0) {
            mask[(size_t)row * WORDS + w] = b;
            cnt += __popcll(b);
        }
    }
    __shared__ unsigned int wred[4];
    if (lane == 0) wred[wave] = cnt;
    __syncthreads();
    if (threadIdx.x == 0)
        degf[row] = (float)(wred[0] + wred[1] + wred[2] + wred[3]);
}

// ---------------- K2: tri via bitset intersect, C = 2*tri/(deg*(deg-1)) ----------------
__global__ __launch_bounds__(256) void k_clust(const unsigned long long* __restrict__ mask,
                                               const float* __restrict__ degf,
                                               float* __restrict__ C) {
    int wave = threadIdx.x >> 6;
    int lane = threadIdx.x & 63;
    int node = blockIdx.x * 4 + wave;
    const unsigned long long* mrow = mask + (size_t)node * WORDS;
    unsigned long long my = mrow[lane];
    unsigned int acc = 0;
    for (int w = 0; w < WORDS; ++w) {
        unsigned long long word = mrow[w];  // wave-uniform
        while (word) {
            int b = __ffsll(word) - 1;
            int j = w * 64 + b;
            acc += __popcll(my & mask[(size_t)j * WORDS + lane]);
            word &= word - 1;
        }
    }
    for (int off = 32; off > 0; off >>= 1) acc += __shfl_xor(acc, off);
    if (lane == 0) {
        float dg = degf[node];
        float denom = dg * (dg - 1.0f);
        if (denom == 0.0f) denom = 1e-6f;
        C[node] = 2.0f * (float)acc / denom;
    }
}

// ---------------- K3: proj[n] = x[n] @ W_proj[type[n]]  (8 nodes/block) ----------------
__global__ __launch_bounds__(128) void k_proj(const float* __restrict__ x,
                                              const int* __restrict__ ntype,
                                              const float* __restrict__ Wp,
                                              float* __restrict__ proj) {
    int base = blockIdx.x * 8;
    int e = threadIdx.x;
    __shared__ float xs[8][DIM];
    __shared__ int ts[8];
    for (int m = 0; m < 8; ++m) xs[m][e] = x[(size_t)(base + m) * DIM + e];
    if (e < 8) ts[e] = ntype[base + e];
    __syncthreads();
    float acc[8] = {0.f, 0.f, 0.f, 0.f, 0.f, 0.f, 0.f, 0.f};
    int tloc[8];
    for (int m = 0; m < 8; ++m) tloc[m] = ts[m];
    for (int t = 0; t < NTYPES; ++t) {
        const float* W = Wp + (size_t)t * DIM * DIM;
        bool any = false;
        for (int m = 0; m < 8; ++m) any |= (tloc[m] == t);
        if (!any) continue;
        for (int d = 0; d < DIM; ++d) {
            float w = W[d * DIM + e];
            #pragma unroll
            for (int m = 0; m < 8; ++m)
                acc[m] += (tloc[m] == t ? xs[m][d] : 0.f) * w;
        }
    }
    for (int m = 0; m < 8; ++m) proj[(size_t)(base + m) * DIM + e] = acc[m];
}

// ---------------- K4a: h[n][r][d] = mean_k x[nidx[n][r][k]][d]  (thread per (n,r,d)) ----------------
__global__ __launch_bounds__(256) void k_hr(const float* __restrict__ x,
                                            const int* __restrict__ nidx,
                                            float* __restrict__ h) {
    int tid = blockIdx.x * 256 + threadIdx.x;   // 4096*4*128 = 2,097,152
    int d  = tid & (DIM - 1);
    int nr = tid >> 7;                          // n*NREL + r
    const int4* idx4 = (const int4*)(nidx + (size_t)nr * NNEIGH);
    int4 i0 = idx4[0], i1 = idx4[1], i2 = idx4[2], i3 = idx4[3];
    float s = 0.f;
    s += x[(size_t)i0.x * DIM + d]; s += x[(size_t)i0.y * DIM + d];
    s += x[(size_t)i0.z * DIM + d]; s += x[(size_t)i0.w * DIM + d];
    s += x[(size_t)i1.x * DIM + d]; s += x[(size_t)i1.y * DIM + d];
    s += x[(size_t)i1.z * DIM + d]; s += x[(size_t)i1.w * DIM + d];
    s += x[(size_t)i2.x * DIM + d]; s += x[(size_t)i2.y * DIM + d];
    s += x[(size_t)i2.z * DIM + d]; s += x[(size_t)i2.w * DIM + d];
    s += x[(size_t)i3.x * DIM + d]; s += x[(size_t)i3.y * DIM + d];
    s += x[(size_t)i3.z * DIM + d]; s += x[(size_t)i3.w * DIM + d];
    h[tid] = s * (1.0f / 16.0f);
}

// ---------------- K4b: eps = sigmoid(mean_r(h_r @ W_beta[r] + b_beta[r]))  (8 nodes/block) ----------------
__global__ __launch_bounds__(128) void k_eps_mm(const float* __restrict__ h,
                                                const float* __restrict__ Wb,
                                                const float* __restrict__ bb,
                                                float* __restrict__ eps) {
    int base = blockIdx.x * 8;
    int e = threadIdx.x;
    __shared__ float hs[8][NREL][DIM];  // 16 KB
    const float* hsrc = h + (size_t)base * NREL * DIM;
    for (int i = threadIdx.x; i < 8 * NREL * DIM; i += 128)
        ((float*)hs)[i] = hsrc[i];
    __syncthreads();
    float acc[8] = {0.f, 0.f, 0.f, 0.f, 0.f, 0.f, 0.f, 0.f};
    for (int r = 0; r < NREL; ++r) {
        const float* W = Wb + (size_t)r * DIM * DIM;
        #pragma unroll 4
        for (int dd = 0; dd < DIM; ++dd) {
            float w = W[dd * DIM + e];
            #pragma unroll
            for (int m = 0; m < 8; ++m) acc[m] += hs[m][r][dd] * w;
        }
    }
    float bsum = bb[e] + bb[DIM + e] + bb[2 * DIM + e] + bb[3 * DIM + e];
    for (int m = 0; m < 8; ++m) {
        float v = (acc[m] + bsum) * 0.25f;
        eps[(size_t)(base + m) * DIM + e] = 1.0f / (1.0f + expf(-v));
    }
}

// ---------------- K5: per-pair fused epilogue (one wave per pair) ----------------
__global__ __launch_bounds__(256) void k_pairs(const int* __restrict__ pairs,
                                               const unsigned long long* __restrict__ mask,
                                               const float* __restrict__ C,
                                               const float* __restrict__ proj,
                                               const float* __restrict__ eps,
                                               const float* __restrict__ x,
                                               const float* __restrict__ salpha_p,
                                               const float* __restrict__ q1p,
                                               const float* __restrict__ q2p,
                                               float* __restrict__ out) {
    int wave = threadIdx.x >> 6;
    int lane = threadIdx.x & 63;
    int p = blockIdx.x * 4 + wave;
    int pm = pairs[p * 2];
    int pn = pairs[p * 2 + 1];

    unsigned long long cw = mask[(size_t)pm * WORDS + lane] & mask[(size_t)pn * WORDS + lane];
    float csum = 0.f;
    while (cw) {
        int b = __ffsll(cw) - 1;
        csum += C[lane * 64 + b];
        cw &= cw - 1;
    }

    float s1 = 0.f, s2 = 0.f, s3 = 0.f;
    #pragma unroll
    for (int i = 0; i < 2; ++i) {
        int d = lane + i * 64;
        float dp = proj[(size_t)pm * DIM + d] - proj[(size_t)pn * DIM + d];
        s1 += dp * dp;
        float dx = x[(size_t)pm * DIM + d] - x[(size_t)pn * DIM + d];
        s2 += dx * dx;
        s3 += eps[(size_t)pm * DIM + d] * eps[(size_t)pn * DIM + d];
    }
    for (int off = 32; off > 0; off >>= 1) {
        s1 += __shfl_xor(s1, off);
        s2 += __shfl_xor(s2, off);
        s3 += __shfl_xor(s3, off);
        csum += __shfl_xor(csum, off);
    }
    if (lane == 0) {
        float lhist  = -sqrtf(s1) + salpha_p[0];
        float ltri   = csum * (-s2);
        float lneigh = s3 * (1.0f / 128.0f);
        float lam = expf(lhist + ltri + lneigh);
        float z = q1p[0] * lam + q2p[0];
        out[p] = 1.0f / (1.0f + expf(-z));
    }
}

extern "C" void kernel_launch(void* const* d_in, const int* in_sizes, int n_in,
                              void* d_out, int out_size, void* d_ws, size_t ws_size,
                              hipStream_t stream) {
    const int*   pairs    = (const int*)d_in[0];
    const int*   adj      = (const int*)d_in[1];
    const int*   nidx     = (const int*)d_in[2];
    const int*   ntype    = (const int*)d_in[3];
    const float* t_events = (const float*)d_in[4];
    const float* x        = (const float*)d_in[5];
    const float* Wp       = (const float*)d_in[6];
    const float* Wb       = (const float*)d_in[7];
    const float* bb       = (const float*)d_in[8];
    const float* theta    = (const float*)d_in[9];
    const float* q1       = (const float*)d_in[10];
    const float* q2       = (const float*)d_in[11];
    float* out = (float*)d_out;

    char* ws = (char*)d_ws;
    unsigned long long* mask = (unsigned long long*)(ws + 0);      // 2 MB
    float* deg    = (float*)(ws + 2097152);                        // 16 KB
    float* C      = (float*)(ws + 2113536);                        // 16 KB
    float* proj   = (float*)(ws + 2129920);                        // 2 MB
    float* eps    = (float*)(ws + 4227072);                        // 2 MB
    float* salpha = (float*)(ws + 6324224);                        // 4 B
    float* h      = (float*)(ws + 6324352);                        // 8 MB  (4096*4*128 f32)

    hipLaunchKernelGGL(k_sum_alpha, dim3(1),             dim3(256), 0, stream, t_events, theta, salpha);
    hipLaunchKernelGGL(k_mask,      dim3(N_NODES),       dim3(256), 0, stream, adj, mask, deg);
    hipLaunchKernelGGL(k_clust,     dim3(N_NODES / 4),   dim3(256), 0, stream, mask, deg, C);
    hipLaunchKernelGGL(k_proj,      dim3(N_NODES / 8),   dim3(128), 0, stream, x, ntype, Wp, proj);
    hipLaunchKernelGGL(k_hr,        dim3(N_NODES * NREL * DIM / 256), dim3(256), 0, stream, x, nidx, h);
    hipLaunchKernelGGL(k_eps_mm,    dim3(N_NODES / 8),   dim3(128), 0, stream, h, Wb, bb, eps);
    hipLaunchKernelGGL(k_pairs,     dim3(NPAIRS / 4),    dim3(256), 0, stream,
                       pairs, mask, C, proj, eps, x, salpha, q1, q2, out);
}

// Round 3
// 119.897 us; speedup vs baseline: 1.7660x; 1.5970x over previous
//
#include <hip/hip_runtime.h>
#include <math.h>

#define N_NODES 4096
#define DIM     128
#define NPAIRS  32768
#define NEVENTS 4096
#define NTYPES  3
#define NREL    4
#define NNEIGH  16
#define WORDS   64   // 4096 bits / 64

// ---------------- K0: sum_alpha = sum(exp(-theta*(1 - t_events))) ----------------
__global__ __launch_bounds__(256) void k_sum_alpha(const float* __restrict__ t_events,
                                                   const float* __restrict__ theta_p,
                                                   float* __restrict__ out) {
    __shared__ float red[256];
    float th = theta_p[0];
    float acc = 0.f;
    for (int i = threadIdx.x; i < NEVENTS; i += 256)
        acc += expf(-th * (1.0f - t_events[i]));
    red[threadIdx.x] = acc;
    __syncthreads();
    for (int s = 128; s > 0; s >>= 1) {
        if (threadIdx.x < s) red[threadIdx.x] += red[threadIdx.x + s];
        __syncthreads();
    }
    if (threadIdx.x == 0) out[0] = red[0];
}

// ---------------- K1: adjacency row -> 64 x u64 bitmask + degree ----------------
__global__ __launch_bounds__(256) void k_mask(const int* __restrict__ adj,
                                              unsigned long long* __restrict__ mask,
                                              float* __restrict__ degf) {
    int row  = blockIdx.x;
    int lane = threadIdx.x & 63;
    int wave = threadIdx.x >> 6;
    const int* arow = adj + (size_t)row * N_NODES;
    unsigned int cnt = 0;
    for (int w = wave; w < WORDS; w += 4) {
        int v = arow[w * 64 + lane];
        unsigned long long b = __ballot(v != 0);
        if (lane == 0) {
            mask[(size_t)row * WORDS + w] = b;
            cnt += __popcll(b);
        }
    }
    __shared__ unsigned int wred[4];
    if (lane == 0) wred[wave] = cnt;
    __syncthreads();
    if (threadIdx.x == 0)
        degf[row] = (float)(wred[0] + wred[1] + wred[2] + wred[3]);
}

// ---------------- K2: tri via bitset intersect, C = 2*tri/(deg*(deg-1)) ----------------
__global__ __launch_bounds__(256) void k_clust(const unsigned long long* __restrict__ mask,
                                               const float* __restrict__ degf,
                                               float* __restrict__ C) {
    int wave = threadIdx.x >> 6;
    int lane = threadIdx.x & 63;
    int node = blockIdx.x * 4 + wave;
    const unsigned long long* mrow = mask + (size_t)node * WORDS;
    unsigned long long my = mrow[lane];
    unsigned int acc = 0;
    for (int w = 0; w < WORDS; ++w) {
        unsigned long long word = mrow[w];  // wave-uniform
        while (word) {
            int b = __ffsll(word) - 1;
            int j = w * 64 + b;
            acc += __popcll(my & mask[(size_t)j * WORDS + lane]);
            word &= word - 1;
        }
    }
    for (int off = 32; off > 0; off >>= 1) acc += __shfl_xor(acc, off);
    if (lane == 0) {
        float dg = degf[node];
        float denom = dg * (dg - 1.0f);
        if (denom == 0.0f) denom = 1e-6f;
        C[node] = 2.0f * (float)acc / denom;
    }
}

// ---------------- K3: proj[n] = x[n] @ W_proj[type[n]]  (node per block, 128 thr) ----------------
__global__ __launch_bounds__(128) void k_proj(const float* __restrict__ x,
                                              const int* __restrict__ ntype,
                                              const float* __restrict__ Wp,
                                              float* __restrict__ proj) {
    int n = blockIdx.x;
    int e = threadIdx.x;
    __shared__ float xs[DIM];
    xs[e] = x[(size_t)n * DIM + e];
    __syncthreads();
    int t = ntype[n];
    const float* W = Wp + (size_t)t * DIM * DIM + e;
    float acc = 0.f;
    #pragma unroll 8
    for (int d = 0; d < DIM; ++d)
        acc += xs[d] * W[(size_t)d * DIM];
    proj[(size_t)n * DIM + e] = acc;
}

// ---------------- K4a: h[n][r][d] = mean_k x[nidx[n][r][k]][d]  (thread per (n,r,d)) ----------------
__global__ __launch_bounds__(256) void k_hr(const float* __restrict__ x,
                                            const int* __restrict__ nidx,
                                            float* __restrict__ h) {
    int tid = blockIdx.x * 256 + threadIdx.x;   // 4096*4*128 = 2,097,152
    int d  = tid & (DIM - 1);
    int nr = tid >> 7;                          // n*NREL + r
    const int4* idx4 = (const int4*)(nidx + (size_t)nr * NNEIGH);
    int4 i0 = idx4[0], i1 = idx4[1], i2 = idx4[2], i3 = idx4[3];
    float s = 0.f;
    s += x[(size_t)i0.x * DIM + d]; s += x[(size_t)i0.y * DIM + d];
    s += x[(size_t)i0.z * DIM + d]; s += x[(size_t)i0.w * DIM + d];
    s += x[(size_t)i1.x * DIM + d]; s += x[(size_t)i1.y * DIM + d];
    s += x[(size_t)i1.z * DIM + d]; s += x[(size_t)i1.w * DIM + d];
    s += x[(size_t)i2.x * DIM + d]; s += x[(size_t)i2.y * DIM + d];
    s += x[(size_t)i2.z * DIM + d]; s += x[(size_t)i2.w * DIM + d];
    s += x[(size_t)i3.x * DIM + d]; s += x[(size_t)i3.y * DIM + d];
    s += x[(size_t)i3.z * DIM + d]; s += x[(size_t)i3.w * DIM + d];
    h[tid] = s * (1.0f / 16.0f);
}

// ---------------- K4b: eps preact = H[4096x512] @ Wcat[512x128], then sigmoid ----------------
// 4 nodes per block, 256 threads: e = tid&127, g = tid>>7; thread handles nodes g, g+2.
__global__ __launch_bounds__(256) void k_eps_mm(const float* __restrict__ h,
                                                const float* __restrict__ Wb,
                                                const float* __restrict__ bb,
                                                float* __restrict__ eps) {
    int base = blockIdx.x * 4;
    int e = threadIdx.x & 127;
    int g = threadIdx.x >> 7;
    __shared__ float hs[4][NREL * DIM];  // 8 KB
    const float* hsrc = h + (size_t)base * NREL * DIM;
    for (int i = threadIdx.x; i < 4 * NREL * DIM; i += 256)
        ((float*)hs)[i] = hsrc[i];
    __syncthreads();
    int m0 = g, m1 = g + 2;
    const float* W = Wb + e;   // Wb flat: [r*128+dd][128] with k = r*128+dd
    float a0 = 0.f, a1 = 0.f;
    #pragma unroll 8
    for (int k = 0; k < NREL * DIM; ++k) {
        float w = W[(size_t)k * DIM];
        a0 += hs[m0][k] * w;
        a1 += hs[m1][k] * w;
    }
    float bsum = bb[e] + bb[DIM + e] + bb[2 * DIM + e] + bb[3 * DIM + e];
    float v0 = (a0 + bsum) * 0.25f;
    float v1 = (a1 + bsum) * 0.25f;
    eps[(size_t)(base + m0) * DIM + e] = 1.0f / (1.0f + expf(-v0));
    eps[(size_t)(base + m1) * DIM + e] = 1.0f / (1.0f + expf(-v1));
}

// ---------------- K5: per-pair fused epilogue (one wave per pair) ----------------
__global__ __launch_bounds__(256) void k_pairs(const int* __restrict__ pairs,
                                               const unsigned long long* __restrict__ mask,
                                               const float* __restrict__ C,
                                               const float* __restrict__ proj,
                                               const float* __restrict__ eps,
                                               const float* __restrict__ x,
                                               const float* __restrict__ salpha_p,
                                               const float* __restrict__ q1p,
                                               const float* __restrict__ q2p,
                                               float* __restrict__ out) {
    int wave = threadIdx.x >> 6;
    int lane = threadIdx.x & 63;
    int p = blockIdx.x * 4 + wave;
    int pm = pairs[p * 2];
    int pn = pairs[p * 2 + 1];

    unsigned long long cw = mask[(size_t)pm * WORDS + lane] & mask[(size_t)pn * WORDS + lane];
    float csum = 0.f;
    while (cw) {
        int b = __ffsll(cw) - 1;
        csum += C[lane * 64 + b];
        cw &= cw - 1;
    }

    float s1 = 0.f, s2 = 0.f, s3 = 0.f;
    #pragma unroll
    for (int i = 0; i < 2; ++i) {
        int d = lane + i * 64;
        float dp = proj[(size_t)pm * DIM + d] - proj[(size_t)pn * DIM + d];
        s1 += dp * dp;
        float dx = x[(size_t)pm * DIM + d] - x[(size_t)pn * DIM + d];
        s2 += dx * dx;
        s3 += eps[(size_t)pm * DIM + d] * eps[(size_t)pn * DIM + d];
    }
    for (int off = 32; off > 0; off >>= 1) {
        s1 += __shfl_xor(s1, off);
        s2 += __shfl_xor(s2, off);
        s3 += __shfl_xor(s3, off);
        csum += __shfl_xor(csum, off);
    }
    if (lane == 0) {
        float lhist  = -sqrtf(s1) + salpha_p[0];
        float ltri   = csum * (-s2);
        float lneigh = s3 * (1.0f / 128.0f);
        float lam = expf(lhist + ltri + lneigh);
        float z = q1p[0] * lam + q2p[0];
        out[p] = 1.0f / (1.0f + expf(-z));
    }
}

extern "C" void kernel_launch(void* const* d_in, const int* in_sizes, int n_in,
                              void* d_out, int out_size, void* d_ws, size_t ws_size,
                              hipStream_t stream) {
    const int*   pairs    = (const int*)d_in[0];
    const int*   adj      = (const int*)d_in[1];
    const int*   nidx     = (const int*)d_in[2];
    const int*   ntype    = (const int*)d_in[3];
    const float* t_events = (const float*)d_in[4];
    const float* x        = (const float*)d_in[5];
    const float* Wp       = (const float*)d_in[6];
    const float* Wb       = (const float*)d_in[7];
    const float* bb       = (const float*)d_in[8];
    const float* theta    = (const float*)d_in[9];
    const float* q1       = (const float*)d_in[10];
    const float* q2       = (const float*)d_in[11];
    float* out = (float*)d_out;

    char* ws = (char*)d_ws;
    unsigned long long* mask = (unsigned long long*)(ws + 0);      // 2 MB
    float* deg    = (float*)(ws + 2097152);                        // 16 KB
    float* C      = (float*)(ws + 2113536);                        // 16 KB
    float* proj   = (float*)(ws + 2129920);                        // 2 MB
    float* eps    = (float*)(ws + 4227072);                        // 2 MB
    float* salpha = (float*)(ws + 6324224);                        // 4 B
    float* h      = (float*)(ws + 6324352);                        // 8 MB  (4096*4*128 f32)

    hipLaunchKernelGGL(k_sum_alpha, dim3(1),             dim3(256), 0, stream, t_events, theta, salpha);
    hipLaunchKernelGGL(k_mask,      dim3(N_NODES),       dim3(256), 0, stream, adj, mask, deg);
    hipLaunchKernelGGL(k_clust,     dim3(N_NODES / 4),   dim3(256), 0, stream, mask, deg, C);
    hipLaunchKernelGGL(k_proj,      dim3(N_NODES),       dim3(128), 0, stream, x, ntype, Wp, proj);
    hipLaunchKernelGGL(k_hr,        dim3(N_NODES * NREL * DIM / 256), dim3(256), 0, stream, x, nidx, h);
    hipLaunchKernelGGL(k_eps_mm,    dim3(N_NODES / 4),   dim3(256), 0, stream, h, Wb, bb, eps);
    hipLaunchKernelGGL(k_pairs,     dim3(NPAIRS / 4),    dim3(256), 0, stream,
                       pairs, mask, C, proj, eps, x, salpha, q1, q2, out);
}

// Round 4
// 101.697 us; speedup vs baseline: 2.0820x; 1.1790x over previous
//
#include <hip/hip_runtime.h>
#include <math.h>

#define N_NODES 4096
#define DIM     128
#define NPAIRS  32768
#define NEVENTS 4096
#define NTYPES  3
#define NREL    4
#define NNEIGH  16
#define WORDS   64   // 4096 bits / 64

// Phase A block ranges
#define PA_MASK_END  N_NODES                   // 4096 blocks: one adj row each
#define PA_PROJ_END  (PA_MASK_END + N_NODES/2) // 2048 blocks: 2 nodes each
#define PA_HR_END    (PA_PROJ_END + N_NODES*NREL*DIM/256) // 8192 blocks
#define PA_TOTAL     (PA_HR_END + 1)           // +1 block: sum_alpha

// ================= Phase A: mask+deg | proj | hr | sum_alpha =================
__global__ __launch_bounds__(256) void k_phaseA(const int* __restrict__ adj,
                                                unsigned long long* __restrict__ mask,
                                                float* __restrict__ degf,
                                                const float* __restrict__ x,
                                                const int* __restrict__ ntype,
                                                const float* __restrict__ Wp,
                                                float* __restrict__ proj,
                                                const int* __restrict__ nidx,
                                                float* __restrict__ h,
                                                const float* __restrict__ t_events,
                                                const float* __restrict__ theta_p,
                                                float* __restrict__ salpha) {
    __shared__ float smem[512];   // reused per branch (2 KB)
    int b = blockIdx.x;

    if (b < PA_MASK_END) {
        // ---- adjacency row -> 64 x u64 bitmask + degree ----
        int row  = b;
        int lane = threadIdx.x & 63;
        int wave = threadIdx.x >> 6;
        const int* arow = adj + (size_t)row * N_NODES;
        unsigned int cnt = 0;
        for (int w = wave; w < WORDS; w += 4) {
            int v = arow[w * 64 + lane];
            unsigned long long bl = __ballot(v != 0);
            if (lane == 0) {
                mask[(size_t)row * WORDS + w] = bl;
                cnt += __popcll(bl);
            }
        }
        unsigned int* wred = (unsigned int*)smem;
        if (lane == 0) wred[wave] = cnt;
        __syncthreads();
        if (threadIdx.x == 0)
            degf[row] = (float)(wred[0] + wred[1] + wred[2] + wred[3]);

    } else if (b < PA_PROJ_END) {
        // ---- proj[n] = x[n] @ W_proj[type[n]], 2 nodes per block ----
        int base = (b - PA_MASK_END) * 2;
        int g = threadIdx.x >> 7;
        int e = threadIdx.x & 127;
        int n = base + g;
        float* xs = smem;  // [2][128]
        xs[g * DIM + e] = x[(size_t)n * DIM + e];
        __syncthreads();
        int t = ntype[n];
        const float* W = Wp + (size_t)t * DIM * DIM + e;
        float acc = 0.f;
        #pragma unroll 8
        for (int d = 0; d < DIM; ++d)
            acc += xs[g * DIM + d] * W[(size_t)d * DIM];
        proj[(size_t)n * DIM + e] = acc;

    } else if (b < PA_HR_END) {
        // ---- h[n][r][d] = mean_k x[nidx[n][r][k]][d] ----
        int tid = (b - PA_PROJ_END) * 256 + threadIdx.x;
        int d  = tid & (DIM - 1);
        int nr = tid >> 7;
        const int4* idx4 = (const int4*)(nidx + (size_t)nr * NNEIGH);
        int4 i0 = idx4[0], i1 = idx4[1], i2 = idx4[2], i3 = idx4[3];
        float s = 0.f;
        s += x[(size_t)i0.x * DIM + d]; s += x[(size_t)i0.y * DIM + d];
        s += x[(size_t)i0.z * DIM + d]; s += x[(size_t)i0.w * DIM + d];
        s += x[(size_t)i1.x * DIM + d]; s += x[(size_t)i1.y * DIM + d];
        s += x[(size_t)i1.z * DIM + d]; s += x[(size_t)i1.w * DIM + d];
        s += x[(size_t)i2.x * DIM + d]; s += x[(size_t)i2.y * DIM + d];
        s += x[(size_t)i2.z * DIM + d]; s += x[(size_t)i2.w * DIM + d];
        s += x[(size_t)i3.x * DIM + d]; s += x[(size_t)i3.y * DIM + d];
        s += x[(size_t)i3.z * DIM + d]; s += x[(size_t)i3.w * DIM + d];
        h[tid] = s * (1.0f / 16.0f);

    } else {
        // ---- sum_alpha ----
        float th = theta_p[0];
        float acc = 0.f;
        for (int i = threadIdx.x; i < NEVENTS; i += 256)
            acc += expf(-th * (1.0f - t_events[i]));
        smem[threadIdx.x] = acc;
        __syncthreads();
        for (int s = 128; s > 0; s >>= 1) {
            if (threadIdx.x < s) smem[threadIdx.x] += smem[threadIdx.x + s];
            __syncthreads();
        }
        if (threadIdx.x == 0) salpha[0] = smem[0];
    }
}

// ================= Phase B: clust | eps_mm =================
__global__ __launch_bounds__(256) void k_phaseB(const unsigned long long* __restrict__ mask,
                                                const float* __restrict__ degf,
                                                float* __restrict__ C,
                                                const float* __restrict__ h,
                                                const float* __restrict__ Wb,
                                                const float* __restrict__ bb,
                                                float* __restrict__ eps) {
    __shared__ float hs[4 * NREL * DIM];  // 8 KB (eps branch only)
    int b = blockIdx.x;

    if (b < N_NODES / 4) {
        // ---- tri via bitset intersect, C = 2*tri/(deg*(deg-1)) ----
        int wave = threadIdx.x >> 6;
        int lane = threadIdx.x & 63;
        int node = b * 4 + wave;
        const unsigned long long* mrow = mask + (size_t)node * WORDS;
        unsigned long long my = mrow[lane];
        unsigned int acc = 0;
        for (int w = 0; w < WORDS; ++w) {
            unsigned long long word = mrow[w];  // wave-uniform
            while (word) {
                int bit = __ffsll(word) - 1;
                int j = w * 64 + bit;
                acc += __popcll(my & mask[(size_t)j * WORDS + lane]);
                word &= word - 1;
            }
        }
        for (int off = 32; off > 0; off >>= 1) acc += __shfl_xor(acc, off);
        if (lane == 0) {
            float dg = degf[node];
            float denom = dg * (dg - 1.0f);
            if (denom == 0.0f) denom = 1e-6f;
            C[node] = 2.0f * (float)acc / denom;
        }

    } else {
        // ---- eps preact = H[4096x512] @ Wcat[512x128], sigmoid ----
        int base = (b - N_NODES / 4) * 4;
        int e = threadIdx.x & 127;
        int g = threadIdx.x >> 7;
        const float* hsrc = h + (size_t)base * NREL * DIM;
        for (int i = threadIdx.x; i < 4 * NREL * DIM; i += 256)
            hs[i] = hsrc[i];
        __syncthreads();
        int m0 = g, m1 = g + 2;
        const float* W = Wb + e;
        float a0 = 0.f, a1 = 0.f;
        #pragma unroll 8
        for (int k = 0; k < NREL * DIM; ++k) {
            float w = W[(size_t)k * DIM];
            a0 += hs[m0 * NREL * DIM + k] * w;
            a1 += hs[m1 * NREL * DIM + k] * w;
        }
        float bsum = bb[e] + bb[DIM + e] + bb[2 * DIM + e] + bb[3 * DIM + e];
        float v0 = (a0 + bsum) * 0.25f;
        float v1 = (a1 + bsum) * 0.25f;
        eps[(size_t)(base + m0) * DIM + e] = 1.0f / (1.0f + expf(-v0));
        eps[(size_t)(base + m1) * DIM + e] = 1.0f / (1.0f + expf(-v1));
    }
}

// ================= Phase C: per-pair fused epilogue (one wave per pair) =================
__global__ __launch_bounds__(256) void k_pairs(const int* __restrict__ pairs,
                                               const unsigned long long* __restrict__ mask,
                                               const float* __restrict__ C,
                                               const float* __restrict__ proj,
                                               const float* __restrict__ eps,
                                               const float* __restrict__ x,
                                               const float* __restrict__ salpha_p,
                                               const float* __restrict__ q1p,
                                               const float* __restrict__ q2p,
                                               float* __restrict__ out) {
    int wave = threadIdx.x >> 6;
    int lane = threadIdx.x & 63;
    int p = blockIdx.x * 4 + wave;
    int pm = pairs[p * 2];
    int pn = pairs[p * 2 + 1];

    unsigned long long cw = mask[(size_t)pm * WORDS + lane] & mask[(size_t)pn * WORDS + lane];
    float csum = 0.f;
    while (cw) {
        int bit = __ffsll(cw) - 1;
        csum += C[lane * 64 + bit];
        cw &= cw - 1;
    }

    // lane covers d = 2*lane, 2*lane+1 via float2 (512 B per wave per load)
    const float2* Am = (const float2*)(proj + (size_t)pm * DIM);
    const float2* An = (const float2*)(proj + (size_t)pn * DIM);
    const float2* Xm = (const float2*)(x    + (size_t)pm * DIM);
    const float2* Xn = (const float2*)(x    + (size_t)pn * DIM);
    const float2* Em = (const float2*)(eps  + (size_t)pm * DIM);
    const float2* En = (const float2*)(eps  + (size_t)pn * DIM);
    float2 am = Am[lane], an = An[lane];
    float2 xm = Xm[lane], xn = Xn[lane];
    float2 em = Em[lane], en = En[lane];

    float dpx = am.x - an.x, dpy = am.y - an.y;
    float s1 = dpx * dpx + dpy * dpy;
    float dxx = xm.x - xn.x, dxy = xm.y - xn.y;
    float s2 = dxx * dxx + dxy * dxy;
    float s3 = em.x * en.x + em.y * en.y;

    for (int off = 32; off > 0; off >>= 1) {
        s1 += __shfl_xor(s1, off);
        s2 += __shfl_xor(s2, off);
        s3 += __shfl_xor(s3, off);
        csum += __shfl_xor(csum, off);
    }
    if (lane == 0) {
        float lhist  = -sqrtf(s1) + salpha_p[0];
        float ltri   = csum * (-s2);
        float lneigh = s3 * (1.0f / 128.0f);
        float lam = expf(lhist + ltri + lneigh);
        float z = q1p[0] * lam + q2p[0];
        out[p] = 1.0f / (1.0f + expf(-z));
    }
}

extern "C" void kernel_launch(void* const* d_in, const int* in_sizes, int n_in,
                              void* d_out, int out_size, void* d_ws, size_t ws_size,
                              hipStream_t stream) {
    const int*   pairs    = (const int*)d_in[0];
    const int*   adj      = (const int*)d_in[1];
    const int*   nidx     = (const int*)d_in[2];
    const int*   ntype    = (const int*)d_in[3];
    const float* t_events = (const float*)d_in[4];
    const float* x        = (const float*)d_in[5];
    const float* Wp       = (const float*)d_in[6];
    const float* Wb       = (const float*)d_in[7];
    const float* bb       = (const float*)d_in[8];
    const float* theta    = (const float*)d_in[9];
    const float* q1       = (const float*)d_in[10];
    const float* q2       = (const float*)d_in[11];
    float* out = (float*)d_out;

    char* ws = (char*)d_ws;
    unsigned long long* mask = (unsigned long long*)(ws + 0);      // 2 MB
    float* deg    = (float*)(ws + 2097152);                        // 16 KB
    float* C      = (float*)(ws + 2113536);                        // 16 KB
    float* proj   = (float*)(ws + 2129920);                        // 2 MB
    float* eps    = (float*)(ws + 4227072);                        // 2 MB
    float* salpha = (float*)(ws + 6324224);                        // 4 B
    float* h      = (float*)(ws + 6324352);                        // 8 MB

    hipLaunchKernelGGL(k_phaseA, dim3(PA_TOTAL),     dim3(256), 0, stream,
                       adj, mask, deg, x, ntype, Wp, proj, nidx, h, t_events, theta, salpha);
    hipLaunchKernelGGL(k_phaseB, dim3(N_NODES / 2),  dim3(256), 0, stream,
                       mask, deg, C, h, Wb, bb, eps);
    hipLaunchKernelGGL(k_pairs,  dim3(NPAIRS / 4),   dim3(256), 0, stream,
                       pairs, mask, C, proj, eps, x, salpha, q1, q2, out);
}

// Round 5
// 91.938 us; speedup vs baseline: 2.3030x; 1.1061x over previous
//
#include <hip/hip_runtime.h>
#include <math.h>

#define N_NODES 4096
#define DIM     128
#define NPAIRS  32768
#define NEVENTS 4096
#define NTYPES  3
#define NREL    4
#define NNEIGH  16
#define WORDS   64   // 4096 bits / 64

// Mask word layout (permuted): word w = ch*4+c (ch=chunk of 256 cols, c=component).
// Bit l of word w  <->  column (w>>2)*256 + l*4 + (w&3).
// Popcount-invariant for degree/tri; consumers recompute column ids.

// Phase A block ranges
#define PA_MASK_END  (N_NODES / 4)                  // 1024 blocks: wave per row
#define PA_PROJ_END  (PA_MASK_END + N_NODES / 2)    // 2048 blocks: 2 nodes each
#define PA_HR_END    (PA_PROJ_END + N_NODES * NREL * DIM / 256) // 8192 blocks
#define PA_TOTAL     (PA_HR_END + 1)                // +1 block: sum_alpha

// ================= Phase A: mask+deg | proj | hr | sum_alpha =================
__global__ __launch_bounds__(256) void k_phaseA(const int* __restrict__ adj,
                                                unsigned long long* __restrict__ mask,
                                                float* __restrict__ degf,
                                                const float* __restrict__ x,
                                                const int* __restrict__ ntype,
                                                const float* __restrict__ Wp,
                                                float* __restrict__ proj,
                                                const int* __restrict__ nidx,
                                                float* __restrict__ h,
                                                const float* __restrict__ t_events,
                                                const float* __restrict__ theta_p,
                                                float* __restrict__ salpha) {
    __shared__ float smem[512];   // 2 KB, reused per branch
    int b = blockIdx.x;

    if (b < PA_MASK_END) {
        // ---- adjacency: wave per row, int4 loads, 4 ballots each, fully unrolled ----
        int wave = threadIdx.x >> 6;
        int lane = threadIdx.x & 63;
        int row  = b * 4 + wave;
        const int4* arow = (const int4*)(adj + (size_t)row * N_NODES);
        unsigned long long* mrow = mask + (size_t)row * WORDS;
        unsigned int cnt = 0;
        #pragma unroll
        for (int ch = 0; ch < 16; ++ch) {
            int4 v = arow[ch * 64 + lane];
            unsigned long long b0 = __ballot(v.x != 0);
            unsigned long long b1 = __ballot(v.y != 0);
            unsigned long long b2 = __ballot(v.z != 0);
            unsigned long long b3 = __ballot(v.w != 0);
            if (lane == 0) {
                mrow[ch * 4 + 0] = b0;
                mrow[ch * 4 + 1] = b1;
                mrow[ch * 4 + 2] = b2;
                mrow[ch * 4 + 3] = b3;
                cnt += __popcll(b0) + __popcll(b1) + __popcll(b2) + __popcll(b3);
            }
        }
        if (lane == 0) degf[row] = (float)cnt;

    } else if (b < PA_PROJ_END) {
        // ---- proj[n] = x[n] @ W_proj[type[n]], 2 nodes per block ----
        int base = (b - PA_MASK_END) * 2;
        int g = threadIdx.x >> 7;
        int e = threadIdx.x & 127;
        int n = base + g;
        float* xs = smem;  // [2][128]
        xs[g * DIM + e] = x[(size_t)n * DIM + e];
        __syncthreads();
        int t = ntype[n];
        const float* W = Wp + (size_t)t * DIM * DIM + e;
        float acc = 0.f;
        #pragma unroll 8
        for (int d = 0; d < DIM; ++d)
            acc += xs[g * DIM + d] * W[(size_t)d * DIM];
        proj[(size_t)n * DIM + e] = acc;

    } else if (b < PA_HR_END) {
        // ---- h[n][r][d] = mean_k x[nidx[n][r][k]][d] ----
        int tid = (b - PA_PROJ_END) * 256 + threadIdx.x;
        int d  = tid & (DIM - 1);
        int nr = tid >> 7;
        const int4* idx4 = (const int4*)(nidx + (size_t)nr * NNEIGH);
        int4 i0 = idx4[0], i1 = idx4[1], i2 = idx4[2], i3 = idx4[3];
        float s = 0.f;
        s += x[(size_t)i0.x * DIM + d]; s += x[(size_t)i0.y * DIM + d];
        s += x[(size_t)i0.z * DIM + d]; s += x[(size_t)i0.w * DIM + d];
        s += x[(size_t)i1.x * DIM + d]; s += x[(size_t)i1.y * DIM + d];
        s += x[(size_t)i1.z * DIM + d]; s += x[(size_t)i1.w * DIM + d];
        s += x[(size_t)i2.x * DIM + d]; s += x[(size_t)i2.y * DIM + d];
        s += x[(size_t)i2.z * DIM + d]; s += x[(size_t)i2.w * DIM + d];
        s += x[(size_t)i3.x * DIM + d]; s += x[(size_t)i3.y * DIM + d];
        s += x[(size_t)i3.z * DIM + d]; s += x[(size_t)i3.w * DIM + d];
        h[tid] = s * (1.0f / 16.0f);

    } else {
        // ---- sum_alpha ----
        float th = theta_p[0];
        float acc = 0.f;
        for (int i = threadIdx.x; i < NEVENTS; i += 256)
            acc += expf(-th * (1.0f - t_events[i]));
        smem[threadIdx.x] = acc;
        __syncthreads();
        for (int s = 128; s > 0; s >>= 1) {
            if (threadIdx.x < s) smem[threadIdx.x] += smem[threadIdx.x + s];
            __syncthreads();
        }
        if (threadIdx.x == 0) salpha[0] = smem[0];
    }
}

// ================= Phase B: clust (block/node) | eps_mm (K-split) =================
__global__ __launch_bounds__(256) void k_phaseB(const unsigned long long* __restrict__ mask,
                                                const float* __restrict__ degf,
                                                float* __restrict__ C,
                                                const float* __restrict__ h,
                                                const float* __restrict__ Wb,
                                                const float* __restrict__ bb,
                                                float* __restrict__ eps) {
    __shared__ float smem[3072];  // 12 KB: eps: hs[4][512] + part[2][4][128]; clust: 4 uints
    int b = blockIdx.x;

    if (b < N_NODES) {
        // ---- tri: block per node; wave handles 16 words via __shfl (no word loads) ----
        int wave = threadIdx.x >> 6;
        int lane = threadIdx.x & 63;
        int node = b;
        unsigned long long my = mask[(size_t)node * WORDS + lane];
        unsigned int acc = 0;
        for (int t = 0; t < 16; ++t) {
            int w = wave * 16 + t;
            unsigned long long word = __shfl(my, w);
            int jbase = (w >> 2) * 256 + (w & 3);
            while (word) {
                int bit = __ffsll(word) - 1;
                int j = jbase + bit * 4;
                acc += __popcll(my & mask[(size_t)j * WORDS + lane]);
                word &= word - 1;
            }
        }
        for (int off = 32; off > 0; off >>= 1) acc += __shfl_xor(acc, off);
        unsigned int* wacc = (unsigned int*)smem;
        if (lane == 0) wacc[wave] = acc;
        __syncthreads();
        if (threadIdx.x == 0) {
            float tri = (float)(wacc[0] + wacc[1] + wacc[2] + wacc[3]);
            float dg = degf[node];
            float denom = dg * (dg - 1.0f);
            if (denom == 0.0f) denom = 1e-6f;
            C[node] = 2.0f * tri / denom;
        }

    } else {
        // ---- eps: 4 nodes/block, K split across wave-halves (g = tid>>7) ----
        int base = (b - N_NODES) * 4;
        int e = threadIdx.x & 127;
        int g = threadIdx.x >> 7;        // k-half
        float* hs = smem;                // [4][512]
        float* part = smem + 2048;       // [2][4][128]
        const float4* hsrc = (const float4*)(h + (size_t)base * NREL * DIM);
        float4* hs4 = (float4*)hs;
        for (int i = threadIdx.x; i < 512; i += 256) hs4[i] = hsrc[i];
        __syncthreads();
        const float* W = Wb + (size_t)(g * 256) * DIM + e;
        float a0 = 0.f, a1 = 0.f, a2 = 0.f, a3 = 0.f;
        int k0 = g * 256;
        #pragma unroll 16
        for (int k = 0; k < 256; ++k) {
            float w = W[(size_t)k * DIM];
            int kk = k0 + k;
            a0 += hs[0 * 512 + kk] * w;
            a1 += hs[1 * 512 + kk] * w;
            a2 += hs[2 * 512 + kk] * w;
            a3 += hs[3 * 512 + kk] * w;
        }
        part[(g * 4 + 0) * 128 + e] = a0;
        part[(g * 4 + 1) * 128 + e] = a1;
        part[(g * 4 + 2) * 128 + e] = a2;
        part[(g * 4 + 3) * 128 + e] = a3;
        __syncthreads();
        if (g == 0) {
            float bsum = bb[e] + bb[DIM + e] + bb[2 * DIM + e] + bb[3 * DIM + e];
            #pragma unroll
            for (int m = 0; m < 4; ++m) {
                float v = (part[m * 128 + e] + part[(4 + m) * 128 + e] + bsum) * 0.25f;
                eps[(size_t)(base + m) * DIM + e] = 1.0f / (1.0f + expf(-v));
            }
        }
    }
}

// ================= Phase C: per-pair fused epilogue (one wave per pair) =================
__global__ __launch_bounds__(256) void k_pairs(const int* __restrict__ pairs,
                                               const unsigned long long* __restrict__ mask,
                                               const float* __restrict__ C,
                                               const float* __restrict__ proj,
                                               const float* __restrict__ eps,
                                               const float* __restrict__ x,
                                               const float* __restrict__ salpha_p,
                                               const float* __restrict__ q1p,
                                               const float* __restrict__ q2p,
                                               float* __restrict__ out) {
    int wave = threadIdx.x >> 6;
    int lane = threadIdx.x & 63;
    int p = blockIdx.x * 4 + wave;
    int pm = pairs[p * 2];
    int pn = pairs[p * 2 + 1];

    unsigned long long cw = mask[(size_t)pm * WORDS + lane] & mask[(size_t)pn * WORDS + lane];
    float csum = 0.f;
    int jbase = (lane >> 2) * 256 + (lane & 3);
    while (cw) {
        int bit = __ffsll(cw) - 1;
        csum += C[jbase + bit * 4];
        cw &= cw - 1;
    }

    const float2* Am = (const float2*)(proj + (size_t)pm * DIM);
    const float2* An = (const float2*)(proj + (size_t)pn * DIM);
    const float2* Xm = (const float2*)(x    + (size_t)pm * DIM);
    const float2* Xn = (const float2*)(x    + (size_t)pn * DIM);
    const float2* Em = (const float2*)(eps  + (size_t)pm * DIM);
    const float2* En = (const float2*)(eps  + (size_t)pn * DIM);
    float2 am = Am[lane], an = An[lane];
    float2 xm = Xm[lane], xn = Xn[lane];
    float2 em = Em[lane], en = En[lane];

    float dpx = am.x - an.x, dpy = am.y - an.y;
    float s1 = dpx * dpx + dpy * dpy;
    float dxx = xm.x - xn.x, dxy = xm.y - xn.y;
    float s2 = dxx * dxx + dxy * dxy;
    float s3 = em.x * en.x + em.y * en.y;

    for (int off = 32; off > 0; off >>= 1) {
        s1 += __shfl_xor(s1, off);
        s2 += __shfl_xor(s2, off);
        s3 += __shfl_xor(s3, off);
        csum += __shfl_xor(csum, off);
    }
    if (lane == 0) {
        float lhist  = -sqrtf(s1) + salpha_p[0];
        float ltri   = csum * (-s2);
        float lneigh = s3 * (1.0f / 128.0f);
        float lam = expf(lhist + ltri + lneigh);
        float z = q1p[0] * lam + q2p[0];
        out[p] = 1.0f / (1.0f + expf(-z));
    }
}

extern "C" void kernel_launch(void* const* d_in, const int* in_sizes, int n_in,
                              void* d_out, int out_size, void* d_ws, size_t ws_size,
                              hipStream_t stream) {
    const int*   pairs    = (const int*)d_in[0];
    const int*   adj      = (const int*)d_in[1];
    const int*   nidx     = (const int*)d_in[2];
    const int*   ntype    = (const int*)d_in[3];
    const float* t_events = (const float*)d_in[4];
    const float* x        = (const float*)d_in[5];
    const float* Wp       = (const float*)d_in[6];
    const float* Wb       = (const float*)d_in[7];
    const float* bb       = (const float*)d_in[8];
    const float* theta    = (const float*)d_in[9];
    const float* q1       = (const float*)d_in[10];
    const float* q2       = (const float*)d_in[11];
    float* out = (float*)d_out;

    char* ws = (char*)d_ws;
    unsigned long long* mask = (unsigned long long*)(ws + 0);      // 2 MB
    float* deg    = (float*)(ws + 2097152);                        // 16 KB
    float* C      = (float*)(ws + 2113536);                        // 16 KB
    float* proj   = (float*)(ws + 2129920);                        // 2 MB
    float* eps    = (float*)(ws + 4227072);                        // 2 MB
    float* salpha = (float*)(ws + 6324224);                        // 4 B
    float* h      = (float*)(ws + 6324352);                        // 8 MB

    hipLaunchKernelGGL(k_phaseA, dim3(PA_TOTAL),              dim3(256), 0, stream,
                       adj, mask, deg, x, ntype, Wp, proj, nidx, h, t_events, theta, salpha);
    hipLaunchKernelGGL(k_phaseB, dim3(N_NODES + N_NODES / 4), dim3(256), 0, stream,
                       mask, deg, C, h, Wb, bb, eps);
    hipLaunchKernelGGL(k_pairs,  dim3(NPAIRS / 4),            dim3(256), 0, stream,
                       pairs, mask, C, proj, eps, x, salpha, q1, q2, out);
}